// Round 5
// baseline (261.993 us; speedup 1.0000x reference)
//
#include <hip/hip_runtime.h>

#define Bsz   32
#define Hh    8
#define Ww    128
#define Cc    512
#define NHEAD 8
#define HD    64
#define NN    1024
#define SCALE 0.125f
#define ROWS  1536

typedef _Float16 f16x8 __attribute__((ext_vector_type(8)));
typedef float    f32x4 __attribute__((ext_vector_type(4)));

// ---------------------------------------------------------------------------
// async global->LDS, 16B per lane (linear dest = wave base + lane*16)
// ---------------------------------------------------------------------------
__device__ __forceinline__ void gload16(const _Float16* g, _Float16* l) {
#if __has_builtin(__builtin_amdgcn_global_load_lds)
  __builtin_amdgcn_global_load_lds(
      (const __attribute__((address_space(1))) unsigned int*)g,
      (__attribute__((address_space(3))) unsigned int*)l, 16, 0, 0);
#else
  *(uint4*)l = *(const uint4*)g;
#endif
}

// ---------------------------------------------------------------------------
// converts
// ---------------------------------------------------------------------------
__global__ __launch_bounds__(256) void cvt_f32_f16(
    const float* __restrict__ in, _Float16* __restrict__ out, int n4) {
  const int i = blockIdx.x * 256 + threadIdx.x;
  if (i < n4) {
    const float4 v = *reinterpret_cast<const float4*>(&in[(size_t)i * 4]);
    _Float16 h[4] = {(_Float16)v.x, (_Float16)v.y, (_Float16)v.z, (_Float16)v.w};
    *reinterpret_cast<uint2*>(&out[(size_t)i * 4]) = *reinterpret_cast<uint2*>(h);
  }
}

// out[n*K + k] = in[k*Nn + n]  (f32 -> f16 transpose)
__global__ __launch_bounds__(256) void tcvt(
    const float* __restrict__ in, _Float16* __restrict__ out, int Nn, int K) {
  const int id = blockIdx.x * 256 + threadIdx.x;
  if (id < Nn * K) {
    const int n = id / K, k = id - n * K;
    out[id] = (_Float16)in[(size_t)k * Nn + n];
  }
}

// ---------------------------------------------------------------------------
// MFMA GEMM: C[M,Nn] = A[M,K](f16) * BT[Nn,K]^T(f16)  (+bias), 128x128 tile,
// BK=32, 4 waves, 4x4 fragments of mfma_f32_16x16x32_f16 per wave.
// ---------------------------------------------------------------------------
template<bool OUT_F16, bool HAS_BIAS>
__global__ __launch_bounds__(256, 2) void gemm_mfma(
    const _Float16* __restrict__ A,
    const _Float16* __restrict__ BT,
    const float* __restrict__ bias,
    void* __restrict__ Cout,
    int Nn, int K)
{
  __shared__ _Float16 As[128 * 32];
  __shared__ _Float16 Bs[128 * 32];

  const int t  = threadIdx.x;
  const int bn = blockIdx.x * 128;
  const int bm = blockIdx.y * 128;
  const int l  = t & 63, wv = t >> 6;
  const int wr = wv >> 1, wc = wv & 1;

  f32x4 acc[4][4] = {};

  const int arow = t >> 2;            // 0..63
  const int ac   = (t & 3) * 8;       // k chunk start (halfs)

  for (int k0 = 0; k0 < K; k0 += 32) {
    __syncthreads();
    gload16(A  + (size_t)(bm + arow)      * K + k0 + ac, &As[t * 8]);
    gload16(A  + (size_t)(bm + 64 + arow) * K + k0 + ac, &As[2048 + t * 8]);
    gload16(BT + (size_t)(bn + arow)      * K + k0 + ac, &Bs[t * 8]);
    gload16(BT + (size_t)(bn + 64 + arow) * K + k0 + ac, &Bs[2048 + t * 8]);
    __syncthreads();

    const int rA = l & 15, ks = (l >> 4) * 8;
    f16x8 aF[4], bF[4];
#pragma unroll
    for (int i = 0; i < 4; ++i)
      aF[i] = *(const f16x8*)&As[(wr * 64 + i * 16 + rA) * 32 + ks];
#pragma unroll
    for (int j = 0; j < 4; ++j)
      bF[j] = *(const f16x8*)&Bs[(wc * 64 + j * 16 + rA) * 32 + ks];
#pragma unroll
    for (int i = 0; i < 4; ++i)
#pragma unroll
      for (int j = 0; j < 4; ++j)
        acc[i][j] = __builtin_amdgcn_mfma_f32_16x16x32_f16(aF[i], bF[j], acc[i][j], 0, 0, 0);
  }

  const int lc = l & 15, lr4 = (l >> 4) * 4;
#pragma unroll
  for (int i = 0; i < 4; ++i) {
    const int row0 = bm + wr * 64 + i * 16 + lr4;
#pragma unroll
    for (int j = 0; j < 4; ++j) {
      const int col = bn + wc * 64 + j * 16 + lc;
      const float bv = HAS_BIAS ? bias[col] : 0.f;
#pragma unroll
      for (int r = 0; r < 4; ++r) {
        const float v = acc[i][j][r] + bv;
        if (OUT_F16)
          ((_Float16*)Cout)[(size_t)(row0 + r) * Nn + col] = (_Float16)v;
        else
          ((float*)Cout)[(size_t)(row0 + r) * Nn + col] = v;
      }
    }
  }
}

// ---------------------------------------------------------------------------
// MFMA local attention, h-paired + XCD-chunked + double-buffered pipeline.
// Block = 1024 wgs remapped so each XCD gets 128 consecutive work-ids (same
// (b,head) quads co-resident -> L2 reuse). 512 thr = 8 waves; wave owns query
// w-tile [w*16,+16) for rows h0,h0+1. Pipeline per key row kr:
//   barrier1 (prev compute done) -> V-waves ds_write V(kr) from regs + load
//   V(kr+1)->regs; K-waves issue gload_lds K(kr+1) into buf^1, counted
//   s_waitcnt vmcnt(4) (K(kr) landed, K(kr+1) stays in flight) -> barrier2
//   -> compute(kr): hoisted kF/vF frags, per-h QK^T mfma, mask, online
//   softmax, P->Pbuf(stride-36, conflict-free), PV mfma.
// Vsh: transposed [d][132-pad] (writes/reads ~2-way, b64 ops, 8B-aligned).
// ---------------------------------------------------------------------------
__global__ __launch_bounds__(512, 4) void local_attn_mfma(
    const _Float16* __restrict__ qkv, _Float16* __restrict__ outh)
{
  const int wg  = blockIdx.x + (Hh / 2) * (blockIdx.y + NHEAD * blockIdx.z);
  const int nid = ((wg & 7) << 7) + (wg >> 3);
  const int hp = nid & 3, head = (nid >> 2) & 7, b = nid >> 5;
  const int h0 = hp * 2;

  const int t = threadIdx.x;
  const int wave = t >> 6, l = t & 63;
  const int g = l >> 4, c = l & 15;
  const int w0 = wave * 16;
  const int kb = min(max(w0 - 8, 0), 96);     // 8-aligned key tile base

  __shared__ _Float16 Ksh[2][8192];           // [buf][col*64 + swz chunk]
  __shared__ _Float16 Vsh[2][64 * 132];       // [buf][d][132-pad cols]
  __shared__ _Float16 Pbuf[8][576];           // [wave][q*36 + z]

  const _Float16* qb = qkv + (size_t)b * NN * ROWS;

  // ---- Q fragments for both h rows (A-frag: row=c, k = s*32 + g*8..+7) ----
  f16x8 qF[2][2];
#pragma unroll
  for (int hi = 0; hi < 2; ++hi) {
    const _Float16* Qg = qb + (size_t)((h0 + hi) * Ww + w0 + c) * ROWS + head * HD;
    qF[hi][0] = *(const f16x8*)&Qg[g * 8];
    qF[hi][1] = *(const f16x8*)&Qg[32 + g * 8];
  }

  // h-independent column masks (per accumulator row r)
  bool cm0[4], cm1[4];
#pragma unroll
  for (int r = 0; r < 4; ++r) {
    const int w = w0 + g * 4 + r;
    cm0[r] = (kb + c      >= w - 5) && (kb + c      <= w + 5);
    cm1[r] = (kb + 16 + c >= w - 5) && (kb + 16 + c <= w + 5);
  }

  const int r0 = max(0, h0 - 3), r1 = min(Hh - 1, h0 + 4);
  float m_run[2][4], s_run[2][4];
  f32x4 accO[2][4] = {};
#pragma unroll
  for (int hi = 0; hi < 2; ++hi)
#pragma unroll
    for (int r = 0; r < 4; ++r) { m_run[hi][r] = -1e30f; s_run[hi][r] = 0.f; }

  // staging coords
  const int jv = t & 255;
  const int dd = jv & 7, cg = jv >> 3;        // V: d-chunk, col-group

  auto issueK = [&](int kr, int pb) {
    const _Float16* Kg = qb + (size_t)(kr * Ww) * ROWS + Cc + head * HD;
#pragma unroll
    for (int i = 0; i < 4; ++i) {
      const int o   = (i * 4 + wave) * 64 + l;       // linear chunk 0..1023
      const int col = o >> 3, dc = o & 7;
      gload16(Kg + (size_t)col * ROWS + ((dc ^ (col & 7)) << 3), &Ksh[pb][o * 8]);
    }
  };
  auto loadV = [&](int kr, f16x8* vr) {
    const _Float16* Vg = qb + (size_t)(kr * Ww + cg * 4) * ROWS + 2 * Cc + head * HD + dd * 8;
#pragma unroll
    for (int i = 0; i < 4; ++i)
      vr[i] = *(const f16x8*)&Vg[(size_t)i * ROWS];
  };

  // ---- prologue: stage kr=r0 ----
  f16x8 vcur[4], vnxt[4];
  if (wave < 4) issueK(r0, r0 & 1);
  else          loadV(r0, vcur);

  for (int kr = r0; kr <= r1; ++kr) {
    const int p = kr & 1;
    __builtin_amdgcn_s_barrier();              // prev compute done
    if (wave >= 4) {
      // write V(kr): Vsh[p][d][col], d=dd*8+e, cols cg*4..+3 (b64, ~2-way)
#pragma unroll
      for (int e = 0; e < 8; ++e) {
        union { _Float16 hh[4]; uint2 u; } pk;
        pk.hh[0] = vcur[0][e]; pk.hh[1] = vcur[1][e];
        pk.hh[2] = vcur[2][e]; pk.hh[3] = vcur[3][e];
        *(uint2*)&Vsh[p][(dd * 8 + e) * 132 + cg * 4] = pk.u;
      }
      if (kr < r1) loadV(kr + 1, vnxt);        // early-issue, lands under compute
      asm volatile("s_waitcnt lgkmcnt(0)" ::: "memory");
    } else {
      if (kr < r1) {
        issueK(kr + 1, p ^ 1);                 // into other buffer
        asm volatile("s_waitcnt vmcnt(4)" ::: "memory");   // K(kr) landed
      } else {
        asm volatile("s_waitcnt vmcnt(0)" ::: "memory");
      }
    }
    __builtin_amdgcn_s_barrier();              // buf p published

    // ---- hoisted fragments (shared by both h rows) ----
    f16x8 kF[2][2];
#pragma unroll
    for (int tt = 0; tt < 2; ++tt) {
      const int col = kb + 16 * tt + c;
#pragma unroll
      for (int s = 0; s < 2; ++s)
        kF[tt][s] = *(const f16x8*)&Ksh[p][col * 64 + (((s * 4 + g) ^ (col & 7)) << 3)];
    }
    union { f16x8 v; uint2 u2[2]; } vF[4];
#pragma unroll
    for (int jj = 0; jj < 4; ++jj) {
      const _Float16* vp = &Vsh[p][(16 * jj + c) * 132 + kb + g * 8];
      vF[jj].u2[0] = *(const uint2*)vp;
      vF[jj].u2[1] = *(const uint2*)(vp + 4);
    }

#pragma unroll
    for (int hi = 0; hi < 2; ++hi) {
      const int hq = h0 + hi;
      if (kr < hq - 3 || kr > hq + 3) continue;

      // ---- QK^T: S[q=g*4+r][kcol = kb + 16*tt + c] ----
      f32x4 accS[2] = {};
#pragma unroll
      for (int tt = 0; tt < 2; ++tt)
#pragma unroll
        for (int s = 0; s < 2; ++s)
          accS[tt] = __builtin_amdgcn_mfma_f32_16x16x32_f16(qF[hi][s], kF[tt][s], accS[tt], 0, 0, 0);

      // ---- mask + online softmax (16-lane-group reduce) ----
      float alpha[4];
#pragma unroll
      for (int r = 0; r < 4; ++r) {
        float s0 = cm0[r] ? accS[0][r] * SCALE : -1e30f;
        float s1 = cm1[r] ? accS[1][r] * SCALE : -1e30f;
        float mx = fmaxf(s0, s1);
#pragma unroll
        for (int msk = 1; msk < 16; msk <<= 1)
          mx = fmaxf(mx, __shfl_xor(mx, msk));
        const float mnew = fmaxf(m_run[hi][r], mx);
        const float p0 = __expf(s0 - mnew);
        const float p1 = __expf(s1 - mnew);
        alpha[r] = __expf(m_run[hi][r] - mnew);
        float ps = p0 + p1;
#pragma unroll
        for (int msk = 1; msk < 16; msk <<= 1)
          ps += __shfl_xor(ps, msk);
        s_run[hi][r] = s_run[hi][r] * alpha[r] + ps;
        m_run[hi][r] = mnew;
        const int q = g * 4 + r;
        Pbuf[wave][q * 36 + c]      = (_Float16)p0;   // bank = 8g + c/2 + const
        Pbuf[wave][q * 36 + 16 + c] = (_Float16)p1;
      }

      // wave-local: drain P writes before re-reading as A-fragment
      asm volatile("s_waitcnt lgkmcnt(0)" ::: "memory");

      // ---- PV: O[q][d=16jj+c] += P(16x32) * V(32x64-window) ----
      union { f16x8 v; uint2 u2[2]; } pF;
      {
        const _Float16* pp = &Pbuf[wave][c * 36 + g * 8];
        pF.u2[0] = *(const uint2*)pp;
        pF.u2[1] = *(const uint2*)(pp + 4);
      }
#pragma unroll
      for (int jj = 0; jj < 4; ++jj)
#pragma unroll
        for (int r = 0; r < 4; ++r) accO[hi][jj][r] *= alpha[r];
#pragma unroll
      for (int jj = 0; jj < 4; ++jj)
        accO[hi][jj] = __builtin_amdgcn_mfma_f32_16x16x32_f16(pF.v, vF[jj].v, accO[hi][jj], 0, 0, 0);
    }

    if (wave >= 4 && kr < r1) {
#pragma unroll
      for (int i = 0; i < 4; ++i) vcur[i] = vnxt[i];
    }
  }

  // ---- epilogue: normalize, store f16 for both h rows ----
#pragma unroll
  for (int hi = 0; hi < 2; ++hi) {
    _Float16* ob = outh + ((size_t)b * NN + (h0 + hi) * Ww + w0) * Cc + head * HD;
#pragma unroll
    for (int r = 0; r < 4; ++r) {
      const float inv = 1.f / s_run[hi][r];
      const int q = g * 4 + r;
#pragma unroll
      for (int jj = 0; jj < 4; ++jj)
        ob[(size_t)q * Cc + 16 * jj + c] = (_Float16)(accO[hi][jj][r] * inv);
    }
  }
}

// ---------------------------------------------------------------------------
extern "C" void kernel_launch(void* const* d_in, const int* in_sizes, int n_in,
                              void* d_out, int out_size, void* d_ws, size_t ws_size,
                              hipStream_t stream)
{
  const float* x      = (const float*)d_in[0];   // [32,1024,512]
  const float* w_qkv  = (const float*)d_in[1];   // [512,1536]
  const float* w_proj = (const float*)d_in[2];   // [512,512]
  const float* b_proj = (const float*)d_in[3];   // [512]
  float* out = (float*)d_out;

  const int M = Bsz * NN;                        // 32768
  char* ws = (char*)d_ws;
  _Float16* xh    = (_Float16*)ws;                              // 33.55 MB
  _Float16* qkvh  = (_Float16*)(ws + 33554432);                 // 100.66 MB
  _Float16* attnh = (_Float16*)(ws + 33554432 + 100663296);     // 33.55 MB
  _Float16* wqT   = (_Float16*)(ws + 167772160);                // 1.57 MB
  _Float16* wpT   = (_Float16*)(ws + 167772160 + 1572864);      // 0.52 MB

  // converts
  cvt_f32_f16<<<(M * Cc / 4 + 255) / 256, 256, 0, stream>>>(x, xh, M * Cc / 4);
  tcvt<<<(ROWS * Cc + 255) / 256, 256, 0, stream>>>(w_qkv, wqT, ROWS, Cc);
  tcvt<<<(Cc * Cc + 255) / 256, 256, 0, stream>>>(w_proj, wpT, Cc, Cc);

  // qkv = x @ w_qkv   (f16 out)
  gemm_mfma<true, false><<<dim3(ROWS / 128, M / 128), 256, 0, stream>>>(
      xh, wqT, nullptr, qkvh, ROWS, Cc);

  // local attention (MFMA, h-paired, double-buffered) -> f16 [32768,512]
  local_attn_mfma<<<dim3(Hh / 2, NHEAD, Bsz), 512, 0, stream>>>(qkvh, attnh);

  // out = attn @ w_proj + bias  (f32 out)
  gemm_mfma<false, true><<<dim3(Cc / 128, M / 128), 256, 0, stream>>>(
      attnh, wpT, b_proj, out, Cc, Cc);
}

// Round 6
// 236.134 us; speedup vs baseline: 1.1095x; 1.1095x over previous
//
#include <hip/hip_runtime.h>

#define Bsz   32
#define Hh    8
#define Ww    128
#define Cc    512
#define NHEAD 8
#define HD    64
#define NN    1024
#define SCALE 0.125f
#define ROWS  1536

typedef _Float16 f16x8 __attribute__((ext_vector_type(8)));
typedef float    f32x4 __attribute__((ext_vector_type(4)));

// ---------------------------------------------------------------------------
// async global->LDS, 16B per lane (linear dest = wave base + lane*16)
// ---------------------------------------------------------------------------
__device__ __forceinline__ void gload16(const _Float16* g, _Float16* l) {
#if __has_builtin(__builtin_amdgcn_global_load_lds)
  __builtin_amdgcn_global_load_lds(
      (const __attribute__((address_space(1))) unsigned int*)g,
      (__attribute__((address_space(3))) unsigned int*)l, 16, 0, 0);
#else
  *(uint4*)l = *(const uint4*)g;
#endif
}

// ---------------------------------------------------------------------------
// converts
// ---------------------------------------------------------------------------
__global__ __launch_bounds__(256) void cvt_f32_f16(
    const float* __restrict__ in, _Float16* __restrict__ out, int n4) {
  const int i = blockIdx.x * 256 + threadIdx.x;
  if (i < n4) {
    const float4 v = *reinterpret_cast<const float4*>(&in[(size_t)i * 4]);
    _Float16 h[4] = {(_Float16)v.x, (_Float16)v.y, (_Float16)v.z, (_Float16)v.w};
    *reinterpret_cast<uint2*>(&out[(size_t)i * 4]) = *reinterpret_cast<uint2*>(h);
  }
}

// out[n*K + k] = in[k*Nn + n]  (f32 -> f16 transpose)
__global__ __launch_bounds__(256) void tcvt(
    const float* __restrict__ in, _Float16* __restrict__ out, int Nn, int K) {
  const int id = blockIdx.x * 256 + threadIdx.x;
  if (id < Nn * K) {
    const int n = id / K, k = id - n * K;
    out[id] = (_Float16)in[(size_t)k * Nn + n];
  }
}

// ---------------------------------------------------------------------------
// MFMA GEMM: C[M,Nn] = A[M,K](f16) * BT[Nn,K]^T(f16)  (+bias), 128x128 tile,
// BK=32, 4 waves, 4x4 fragments of mfma_f32_16x16x32_f16 per wave.
// ---------------------------------------------------------------------------
template<bool OUT_F16, bool HAS_BIAS>
__global__ __launch_bounds__(256, 2) void gemm_mfma(
    const _Float16* __restrict__ A,
    const _Float16* __restrict__ BT,
    const float* __restrict__ bias,
    void* __restrict__ Cout,
    int Nn, int K)
{
  __shared__ _Float16 As[128 * 32];
  __shared__ _Float16 Bs[128 * 32];

  const int t  = threadIdx.x;
  const int bn = blockIdx.x * 128;
  const int bm = blockIdx.y * 128;
  const int l  = t & 63, wv = t >> 6;
  const int wr = wv >> 1, wc = wv & 1;

  f32x4 acc[4][4] = {};

  const int arow = t >> 2;            // 0..63
  const int ac   = (t & 3) * 8;       // k chunk start (halfs)

  for (int k0 = 0; k0 < K; k0 += 32) {
    __syncthreads();
    gload16(A  + (size_t)(bm + arow)      * K + k0 + ac, &As[t * 8]);
    gload16(A  + (size_t)(bm + 64 + arow) * K + k0 + ac, &As[2048 + t * 8]);
    gload16(BT + (size_t)(bn + arow)      * K + k0 + ac, &Bs[t * 8]);
    gload16(BT + (size_t)(bn + 64 + arow) * K + k0 + ac, &Bs[2048 + t * 8]);
    __syncthreads();

    const int rA = l & 15, ks = (l >> 4) * 8;
    f16x8 aF[4], bF[4];
#pragma unroll
    for (int i = 0; i < 4; ++i)
      aF[i] = *(const f16x8*)&As[(wr * 64 + i * 16 + rA) * 32 + ks];
#pragma unroll
    for (int j = 0; j < 4; ++j)
      bF[j] = *(const f16x8*)&Bs[(wc * 64 + j * 16 + rA) * 32 + ks];
#pragma unroll
    for (int i = 0; i < 4; ++i)
#pragma unroll
      for (int j = 0; j < 4; ++j)
        acc[i][j] = __builtin_amdgcn_mfma_f32_16x16x32_f16(aF[i], bF[j], acc[i][j], 0, 0, 0);
  }

  const int lc = l & 15, lr4 = (l >> 4) * 4;
#pragma unroll
  for (int i = 0; i < 4; ++i) {
    const int row0 = bm + wr * 64 + i * 16 + lr4;
#pragma unroll
    for (int j = 0; j < 4; ++j) {
      const int col = bn + wc * 64 + j * 16 + lc;
      const float bv = HAS_BIAS ? bias[col] : 0.f;
#pragma unroll
      for (int r = 0; r < 4; ++r) {
        const float v = acc[i][j][r] + bv;
        if (OUT_F16)
          ((_Float16*)Cout)[(size_t)(row0 + r) * Nn + col] = (_Float16)v;
        else
          ((float*)Cout)[(size_t)(row0 + r) * Nn + col] = v;
      }
    }
  }
}

// ---------------------------------------------------------------------------
// MFMA local attention, h-paired + XCD-chunked; K double-buffered via
// global_load_lds (0 VGPR cost) with counted vmcnt, V synchronous reg-staged
// (transient regs only -- round 5's persistent V pipeline spilled to scratch:
// WRITE_SIZE 37->193MB; this keeps peak VGPR < the 128 cap).
// Per key row kr: barrier (prev compute done) -> K-waves issue K(kr+1) into
// buf^1 + vmcnt(4) [K(kr) landed, K(kr+1) in flight across compute]; V-waves
// load V(kr)->regs, ds_write transposed [d][132-pad], lgkmcnt(0) -> barrier
// -> compute(kr): hoisted kF/vF, per-h QK^T mfma, mask, online softmax
// (16-lane shfl), P->Pbuf (stride 36, conflict-free), PV mfma.
// ---------------------------------------------------------------------------
__global__ __launch_bounds__(512, 4) void local_attn_mfma(
    const _Float16* __restrict__ qkv, _Float16* __restrict__ outh)
{
  const int wg  = blockIdx.x + (Hh / 2) * (blockIdx.y + NHEAD * blockIdx.z);
  const int nid = ((wg & 7) << 7) + (wg >> 3);
  const int hp = nid & 3, head = (nid >> 2) & 7, b = nid >> 5;
  const int h0 = hp * 2;

  const int t = threadIdx.x;
  const int wave = t >> 6, l = t & 63;
  const int g = l >> 4, c = l & 15;
  const int w0 = wave * 16;
  const int kb = min(max(w0 - 8, 0), 96);     // 8-aligned key tile base

  __shared__ _Float16 Ksh[2][8192];           // [buf][col*64 + swz chunk]
  __shared__ _Float16 Vsh[64 * 132];          // [d][132-pad cols]
  __shared__ _Float16 Pbuf[8][576];           // [wave][q*36 + z]

  const _Float16* qb = qkv + (size_t)b * NN * ROWS;

  // ---- Q fragments for both h rows (A-frag: row=c, k = s*32 + g*8..+7) ----
  f16x8 qF[2][2];
#pragma unroll
  for (int hi = 0; hi < 2; ++hi) {
    const _Float16* Qg = qb + (size_t)((h0 + hi) * Ww + w0 + c) * ROWS + head * HD;
    qF[hi][0] = *(const f16x8*)&Qg[g * 8];
    qF[hi][1] = *(const f16x8*)&Qg[32 + g * 8];
  }

  // h-independent column masks (per accumulator row r)
  bool cm0[4], cm1[4];
#pragma unroll
  for (int r = 0; r < 4; ++r) {
    const int w = w0 + g * 4 + r;
    cm0[r] = (kb + c      >= w - 5) && (kb + c      <= w + 5);
    cm1[r] = (kb + 16 + c >= w - 5) && (kb + 16 + c <= w + 5);
  }

  const int r0 = max(0, h0 - 3), r1 = min(Hh - 1, h0 + 4);
  float m_run[2][4], s_run[2][4];
  f32x4 accO[2][4] = {};
#pragma unroll
  for (int hi = 0; hi < 2; ++hi)
#pragma unroll
    for (int r = 0; r < 4; ++r) { m_run[hi][r] = -1e30f; s_run[hi][r] = 0.f; }

  // staging coords (V-waves)
  const int jv = t & 255;
  const int dd = jv & 7, cg = jv >> 3;        // d-chunk, col-group

  auto issueK = [&](int kr, int pb) {
    const _Float16* Kg = qb + (size_t)(kr * Ww) * ROWS + Cc + head * HD;
#pragma unroll
    for (int i = 0; i < 4; ++i) {
      const int o   = (i * 4 + wave) * 64 + l;       // linear chunk 0..1023
      const int col = o >> 3, dc = o & 7;
      gload16(Kg + (size_t)col * ROWS + ((dc ^ (col & 7)) << 3), &Ksh[pb][o * 8]);
    }
  };

  // ---- prologue: issue K(r0) ----
  if (wave < 4) issueK(r0, r0 & 1);

  for (int kr = r0; kr <= r1; ++kr) {
    const int p = kr & 1;
    __builtin_amdgcn_s_barrier();              // prev compute done
    if (wave < 4) {
      if (kr < r1) {
        issueK(kr + 1, p ^ 1);                 // into other buffer
        asm volatile("s_waitcnt vmcnt(4)" ::: "memory");   // K(kr) landed
      } else {
        asm volatile("s_waitcnt vmcnt(0)" ::: "memory");
      }
    } else {
      // V(kr): load 4 cols x 8 d -> transient regs, write transposed
      f16x8 vr[4];
      const _Float16* Vg = qb + (size_t)(kr * Ww + cg * 4) * ROWS + 2 * Cc + head * HD + dd * 8;
#pragma unroll
      for (int i = 0; i < 4; ++i)
        vr[i] = *(const f16x8*)&Vg[(size_t)i * ROWS];
#pragma unroll
      for (int e = 0; e < 8; ++e) {
        union { _Float16 hh[4]; uint2 u; } pk;
        pk.hh[0] = vr[0][e]; pk.hh[1] = vr[1][e];
        pk.hh[2] = vr[2][e]; pk.hh[3] = vr[3][e];
        *(uint2*)&Vsh[(dd * 8 + e) * 132 + cg * 4] = pk.u;
      }
      asm volatile("s_waitcnt lgkmcnt(0)" ::: "memory");
    }
    __builtin_amdgcn_s_barrier();              // Ksh[p], Vsh published

    // ---- hoisted fragments (shared by both h rows) ----
    f16x8 kF[2][2];
#pragma unroll
    for (int tt = 0; tt < 2; ++tt) {
      const int col = kb + 16 * tt + c;
#pragma unroll
      for (int s = 0; s < 2; ++s)
        kF[tt][s] = *(const f16x8*)&Ksh[p][col * 64 + (((s * 4 + g) ^ (col & 7)) << 3)];
    }
    union { f16x8 v; uint2 u2[2]; } vF[4];
#pragma unroll
    for (int jj = 0; jj < 4; ++jj) {
      const _Float16* vp = &Vsh[(16 * jj + c) * 132 + kb + g * 8];
      vF[jj].u2[0] = *(const uint2*)vp;
      vF[jj].u2[1] = *(const uint2*)(vp + 4);
    }

#pragma unroll
    for (int hi = 0; hi < 2; ++hi) {
      const int hq = h0 + hi;
      if (kr < hq - 3 || kr > hq + 3) continue;

      // ---- QK^T: S[q=g*4+r][kcol = kb + 16*tt + c] ----
      f32x4 accS[2] = {};
#pragma unroll
      for (int tt = 0; tt < 2; ++tt)
#pragma unroll
        for (int s = 0; s < 2; ++s)
          accS[tt] = __builtin_amdgcn_mfma_f32_16x16x32_f16(qF[hi][s], kF[tt][s], accS[tt], 0, 0, 0);

      // ---- mask + online softmax (16-lane-group reduce) ----
      float alpha[4];
#pragma unroll
      for (int r = 0; r < 4; ++r) {
        float s0 = cm0[r] ? accS[0][r] * SCALE : -1e30f;
        float s1 = cm1[r] ? accS[1][r] * SCALE : -1e30f;
        float mx = fmaxf(s0, s1);
#pragma unroll
        for (int msk = 1; msk < 16; msk <<= 1)
          mx = fmaxf(mx, __shfl_xor(mx, msk));
        const float mnew = fmaxf(m_run[hi][r], mx);
        const float p0 = __expf(s0 - mnew);
        const float p1 = __expf(s1 - mnew);
        alpha[r] = __expf(m_run[hi][r] - mnew);
        float ps = p0 + p1;
#pragma unroll
        for (int msk = 1; msk < 16; msk <<= 1)
          ps += __shfl_xor(ps, msk);
        s_run[hi][r] = s_run[hi][r] * alpha[r] + ps;
        m_run[hi][r] = mnew;
        const int q = g * 4 + r;
        Pbuf[wave][q * 36 + c]      = (_Float16)p0;   // bank = 8g + c/2 + const
        Pbuf[wave][q * 36 + 16 + c] = (_Float16)p1;
      }

      // wave-local: drain P writes before re-reading as A-fragment
      asm volatile("s_waitcnt lgkmcnt(0)" ::: "memory");

      // ---- PV: O[q][d=16jj+c] += P(16x32) * V(32x64-window) ----
      union { f16x8 v; uint2 u2[2]; } pF;
      {
        const _Float16* pp = &Pbuf[wave][c * 36 + g * 8];
        pF.u2[0] = *(const uint2*)pp;
        pF.u2[1] = *(const uint2*)(pp + 4);
      }
#pragma unroll
      for (int jj = 0; jj < 4; ++jj)
#pragma unroll
        for (int r = 0; r < 4; ++r) accO[hi][jj][r] *= alpha[r];
#pragma unroll
      for (int jj = 0; jj < 4; ++jj)
        accO[hi][jj] = __builtin_amdgcn_mfma_f32_16x16x32_f16(pF.v, vF[jj].v, accO[hi][jj], 0, 0, 0);
    }
  }

  // ---- epilogue: normalize, store f16 for both h rows ----
#pragma unroll
  for (int hi = 0; hi < 2; ++hi) {
    _Float16* ob = outh + ((size_t)b * NN + (h0 + hi) * Ww + w0) * Cc + head * HD;
#pragma unroll
    for (int r = 0; r < 4; ++r) {
      const float inv = 1.f / s_run[hi][r];
      const int q = g * 4 + r;
#pragma unroll
      for (int jj = 0; jj < 4; ++jj)
        ob[(size_t)q * Cc + 16 * jj + c] = (_Float16)(accO[hi][jj][r] * inv);
    }
  }
}

// ---------------------------------------------------------------------------
extern "C" void kernel_launch(void* const* d_in, const int* in_sizes, int n_in,
                              void* d_out, int out_size, void* d_ws, size_t ws_size,
                              hipStream_t stream)
{
  const float* x      = (const float*)d_in[0];   // [32,1024,512]
  const float* w_qkv  = (const float*)d_in[1];   // [512,1536]
  const float* w_proj = (const float*)d_in[2];   // [512,512]
  const float* b_proj = (const float*)d_in[3];   // [512]
  float* out = (float*)d_out;

  const int M = Bsz * NN;                        // 32768
  char* ws = (char*)d_ws;
  _Float16* xh    = (_Float16*)ws;                              // 33.55 MB
  _Float16* qkvh  = (_Float16*)(ws + 33554432);                 // 100.66 MB
  _Float16* attnh = (_Float16*)(ws + 33554432 + 100663296);     // 33.55 MB
  _Float16* wqT   = (_Float16*)(ws + 167772160);                // 1.57 MB
  _Float16* wpT   = (_Float16*)(ws + 167772160 + 1572864);      // 0.52 MB

  // converts
  cvt_f32_f16<<<(M * Cc / 4 + 255) / 256, 256, 0, stream>>>(x, xh, M * Cc / 4);
  tcvt<<<(ROWS * Cc + 255) / 256, 256, 0, stream>>>(w_qkv, wqT, ROWS, Cc);
  tcvt<<<(Cc * Cc + 255) / 256, 256, 0, stream>>>(w_proj, wpT, Cc, Cc);

  // qkv = x @ w_qkv   (f16 out)
  gemm_mfma<true, false><<<dim3(ROWS / 128, M / 128), 256, 0, stream>>>(
      xh, wqT, nullptr, qkvh, ROWS, Cc);

  // local attention (MFMA, h-paired, K-dbuf) -> f16 [32768,512]
  local_attn_mfma<<<dim3(Hh / 2, NHEAD, Bsz), 512, 0, stream>>>(qkvh, attnh);

  // out = attn @ w_proj + bias  (f32 out)
  gemm_mfma<false, true><<<dim3(Cc / 128, M / 128), 256, 0, stream>>>(
      attnh, wpT, b_proj, out, Cc, Cc);
}

// Round 7
// 216.596 us; speedup vs baseline: 1.2096x; 1.0902x over previous
//
#include <hip/hip_runtime.h>

#define Bsz   32
#define Hh    8
#define Ww    128
#define Cc    512
#define NHEAD 8
#define HD    64
#define NN    1024
#define SCALE 0.125f
#define ROWS  1536

typedef _Float16 f16x8 __attribute__((ext_vector_type(8)));
typedef float    f32x4 __attribute__((ext_vector_type(4)));

// ---------------------------------------------------------------------------
// async global->LDS, 16B per lane (linear dest = wave base + lane*16)
// ---------------------------------------------------------------------------
__device__ __forceinline__ void gload16(const _Float16* g, _Float16* l) {
#if __has_builtin(__builtin_amdgcn_global_load_lds)
  __builtin_amdgcn_global_load_lds(
      (const __attribute__((address_space(1))) unsigned int*)g,
      (__attribute__((address_space(3))) unsigned int*)l, 16, 0, 0);
#else
  *(uint4*)l = *(const uint4*)g;
#endif
}

// ---------------------------------------------------------------------------
// converts
// ---------------------------------------------------------------------------
__global__ __launch_bounds__(256) void cvt_f32_f16(
    const float* __restrict__ in, _Float16* __restrict__ out, int n4) {
  const int i = blockIdx.x * 256 + threadIdx.x;
  if (i < n4) {
    const float4 v = *reinterpret_cast<const float4*>(&in[(size_t)i * 4]);
    _Float16 h[4] = {(_Float16)v.x, (_Float16)v.y, (_Float16)v.z, (_Float16)v.w};
    *reinterpret_cast<uint2*>(&out[(size_t)i * 4]) = *reinterpret_cast<uint2*>(h);
  }
}

// out[n*K + k] = in[k*Nn + n]  (f32 -> f16 transpose)
__global__ __launch_bounds__(256) void tcvt(
    const float* __restrict__ in, _Float16* __restrict__ out, int Nn, int K) {
  const int id = blockIdx.x * 256 + threadIdx.x;
  if (id < Nn * K) {
    const int n = id / K, k = id - n * K;
    out[id] = (_Float16)in[(size_t)k * Nn + n];
  }
}

// ---------------------------------------------------------------------------
// MFMA GEMM: C[M,Nn] = A[M,K](f16) * BT[Nn,K]^T(f16)  (+bias), 128x128 tile,
// BK=32, 4 waves, 4x4 fragments of mfma_f32_16x16x32_f16 per wave.
// ---------------------------------------------------------------------------
template<bool OUT_F16, bool HAS_BIAS>
__global__ __launch_bounds__(256, 2) void gemm_mfma(
    const _Float16* __restrict__ A,
    const _Float16* __restrict__ BT,
    const float* __restrict__ bias,
    void* __restrict__ Cout,
    int Nn, int K)
{
  __shared__ _Float16 As[128 * 32];
  __shared__ _Float16 Bs[128 * 32];

  const int t  = threadIdx.x;
  const int bn = blockIdx.x * 128;
  const int bm = blockIdx.y * 128;
  const int l  = t & 63, wv = t >> 6;
  const int wr = wv >> 1, wc = wv & 1;

  f32x4 acc[4][4] = {};

  const int arow = t >> 2;            // 0..63
  const int ac   = (t & 3) * 8;       // k chunk start (halfs)

  for (int k0 = 0; k0 < K; k0 += 32) {
    __syncthreads();
    gload16(A  + (size_t)(bm + arow)      * K + k0 + ac, &As[t * 8]);
    gload16(A  + (size_t)(bm + 64 + arow) * K + k0 + ac, &As[2048 + t * 8]);
    gload16(BT + (size_t)(bn + arow)      * K + k0 + ac, &Bs[t * 8]);
    gload16(BT + (size_t)(bn + 64 + arow) * K + k0 + ac, &Bs[2048 + t * 8]);
    __syncthreads();

    const int rA = l & 15, ks = (l >> 4) * 8;
    f16x8 aF[4], bF[4];
#pragma unroll
    for (int i = 0; i < 4; ++i)
      aF[i] = *(const f16x8*)&As[(wr * 64 + i * 16 + rA) * 32 + ks];
#pragma unroll
    for (int j = 0; j < 4; ++j)
      bF[j] = *(const f16x8*)&Bs[(wc * 64 + j * 16 + rA) * 32 + ks];
#pragma unroll
    for (int i = 0; i < 4; ++i)
#pragma unroll
      for (int j = 0; j < 4; ++j)
        acc[i][j] = __builtin_amdgcn_mfma_f32_16x16x32_f16(aF[i], bF[j], acc[i][j], 0, 0, 0);
  }

  const int lc = l & 15, lr4 = (l >> 4) * 4;
#pragma unroll
  for (int i = 0; i < 4; ++i) {
    const int row0 = bm + wr * 64 + i * 16 + lr4;
#pragma unroll
    for (int j = 0; j < 4; ++j) {
      const int col = bn + wc * 64 + j * 16 + lc;
      const float bv = HAS_BIAS ? bias[col] : 0.f;
#pragma unroll
      for (int r = 0; r < 4; ++r) {
        const float v = acc[i][j][r] + bv;
        if (OUT_F16)
          ((_Float16*)Cout)[(size_t)(row0 + r) * Nn + col] = (_Float16)v;
        else
          ((float*)Cout)[(size_t)(row0 + r) * Nn + col] = v;
      }
    }
  }
}

// ---------------------------------------------------------------------------
// MFMA local attention, h-paired + XCD-chunked; K double-buffered via
// global_load_lds (0 VGPR) with counted vmcnt(4); V synchronous reg-staged
// (transient regs only). NO kF/vF hoisting: fragments are read transiently
// inside each hi-pass -- hoisting them (rounds 5/6) pushed the live set past
// the 128-VGPR cap and spilled ~46MB to scratch (WRITE_SIZE 37->80MB).
// Per key row kr: barrier -> K-waves issue K(kr+1) into buf^1, vmcnt(4);
// V-waves load V(kr)->regs, ds_write transposed [d][132-pad], lgkmcnt(0)
// -> barrier -> compute(kr): per-h QK^T mfma, mask, online softmax (16-lane
// shfl), P->Pbuf (stride-36, conflict-free), PV mfma.
// ---------------------------------------------------------------------------
__global__ __launch_bounds__(512, 4) void local_attn_mfma(
    const _Float16* __restrict__ qkv, _Float16* __restrict__ outh)
{
  const int wg  = blockIdx.x + (Hh / 2) * (blockIdx.y + NHEAD * blockIdx.z);
  const int nid = ((wg & 7) << 7) + (wg >> 3);
  const int hp = nid & 3, head = (nid >> 2) & 7, b = nid >> 5;
  const int h0 = hp * 2;

  const int t = threadIdx.x;
  const int wave = t >> 6, l = t & 63;
  const int g = l >> 4, c = l & 15;
  const int w0 = wave * 16;
  const int kb = min(max(w0 - 8, 0), 96);     // 8-aligned key tile base

  __shared__ _Float16 Ksh[2][8192];           // [buf][col*64 + swz chunk]
  __shared__ _Float16 Vsh[64 * 132];          // [d][132-pad cols]
  __shared__ _Float16 Pbuf[8][576];           // [wave][q*36 + z]

  const _Float16* qb = qkv + (size_t)b * NN * ROWS;

  // ---- Q fragments for both h rows (A-frag: row=c, k = s*32 + g*8..+7) ----
  f16x8 qF[2][2];
#pragma unroll
  for (int hi = 0; hi < 2; ++hi) {
    const _Float16* Qg = qb + (size_t)((h0 + hi) * Ww + w0 + c) * ROWS + head * HD;
    qF[hi][0] = *(const f16x8*)&Qg[g * 8];
    qF[hi][1] = *(const f16x8*)&Qg[32 + g * 8];
  }

  // h-independent column masks (per accumulator row r)
  bool cm0[4], cm1[4];
#pragma unroll
  for (int r = 0; r < 4; ++r) {
    const int w = w0 + g * 4 + r;
    cm0[r] = (kb + c      >= w - 5) && (kb + c      <= w + 5);
    cm1[r] = (kb + 16 + c >= w - 5) && (kb + 16 + c <= w + 5);
  }

  const int r0 = max(0, h0 - 3), r1 = min(Hh - 1, h0 + 4);
  float m_run[2][4], s_run[2][4];
  f32x4 accO[2][4] = {};
#pragma unroll
  for (int hi = 0; hi < 2; ++hi)
#pragma unroll
    for (int r = 0; r < 4; ++r) { m_run[hi][r] = -1e30f; s_run[hi][r] = 0.f; }

  // staging coords (V-waves)
  const int jv = t & 255;
  const int dd = jv & 7, cg = jv >> 3;        // d-chunk, col-group

  auto issueK = [&](int kr, int pb) {
    const _Float16* Kg = qb + (size_t)(kr * Ww) * ROWS + Cc + head * HD;
#pragma unroll
    for (int i = 0; i < 4; ++i) {
      const int o   = (i * 4 + wave) * 64 + l;       // linear chunk 0..1023
      const int col = o >> 3, dc = o & 7;
      gload16(Kg + (size_t)col * ROWS + ((dc ^ (col & 7)) << 3), &Ksh[pb][o * 8]);
    }
  };

  // ---- prologue: issue K(r0) ----
  if (wave < 4) issueK(r0, r0 & 1);

  for (int kr = r0; kr <= r1; ++kr) {
    const int p = kr & 1;
    __builtin_amdgcn_s_barrier();              // prev compute done
    if (wave < 4) {
      if (kr < r1) {
        issueK(kr + 1, p ^ 1);                 // into other buffer
        asm volatile("s_waitcnt vmcnt(4)" ::: "memory");   // K(kr) landed
      } else {
        asm volatile("s_waitcnt vmcnt(0)" ::: "memory");
      }
    } else {
      // V(kr): load 4 cols x 8 d -> transient regs, write transposed
      f16x8 vr[4];
      const _Float16* Vg = qb + (size_t)(kr * Ww + cg * 4) * ROWS + 2 * Cc + head * HD + dd * 8;
#pragma unroll
      for (int i = 0; i < 4; ++i)
        vr[i] = *(const f16x8*)&Vg[(size_t)i * ROWS];
#pragma unroll
      for (int e = 0; e < 8; ++e) {
        union { _Float16 hh[4]; uint2 u; } pk;
        pk.hh[0] = vr[0][e]; pk.hh[1] = vr[1][e];
        pk.hh[2] = vr[2][e]; pk.hh[3] = vr[3][e];
        *(uint2*)&Vsh[(dd * 8 + e) * 132 + cg * 4] = pk.u;
      }
      asm volatile("s_waitcnt lgkmcnt(0)" ::: "memory");
    }
    __builtin_amdgcn_s_barrier();              // Ksh[p], Vsh published

#pragma unroll
    for (int hi = 0; hi < 2; ++hi) {
      const int hq = h0 + hi;
      if (kr < hq - 3 || kr > hq + 3) continue;

      // ---- QK^T: S[q=g*4+r][kcol = kb + 16*tt + c] (kF read transiently) ----
      f32x4 accS[2] = {};
#pragma unroll
      for (int tt = 0; tt < 2; ++tt) {
        const int col = kb + 16 * tt + c;
#pragma unroll
        for (int s = 0; s < 2; ++s) {
          const f16x8 kF = *(const f16x8*)&Ksh[p][col * 64 + (((s * 4 + g) ^ (col & 7)) << 3)];
          accS[tt] = __builtin_amdgcn_mfma_f32_16x16x32_f16(qF[hi][s], kF, accS[tt], 0, 0, 0);
        }
      }

      // ---- mask + online softmax (16-lane-group reduce) ----
      float alpha[4];
#pragma unroll
      for (int r = 0; r < 4; ++r) {
        float s0 = cm0[r] ? accS[0][r] * SCALE : -1e30f;
        float s1 = cm1[r] ? accS[1][r] * SCALE : -1e30f;
        float mx = fmaxf(s0, s1);
#pragma unroll
        for (int msk = 1; msk < 16; msk <<= 1)
          mx = fmaxf(mx, __shfl_xor(mx, msk));
        const float mnew = fmaxf(m_run[hi][r], mx);
        const float p0 = __expf(s0 - mnew);
        const float p1 = __expf(s1 - mnew);
        alpha[r] = __expf(m_run[hi][r] - mnew);
        float ps = p0 + p1;
#pragma unroll
        for (int msk = 1; msk < 16; msk <<= 1)
          ps += __shfl_xor(ps, msk);
        s_run[hi][r] = s_run[hi][r] * alpha[r] + ps;
        m_run[hi][r] = mnew;
        const int q = g * 4 + r;
        Pbuf[wave][q * 36 + c]      = (_Float16)p0;   // bank = 8g + c/2 + const
        Pbuf[wave][q * 36 + 16 + c] = (_Float16)p1;
      }

      // wave-local: drain P writes before re-reading as A-fragment
      asm volatile("s_waitcnt lgkmcnt(0)" ::: "memory");

      // ---- PV: O[q][d=16jj+c] += P(16x32) * V(32x64-window) ----
      union { f16x8 v; uint2 u2[2]; } pF;
      {
        const _Float16* pp = &Pbuf[wave][c * 36 + g * 8];
        pF.u2[0] = *(const uint2*)pp;
        pF.u2[1] = *(const uint2*)(pp + 4);
      }
#pragma unroll
      for (int jj = 0; jj < 4; ++jj)
#pragma unroll
        for (int r = 0; r < 4; ++r) accO[hi][jj][r] *= alpha[r];
#pragma unroll
      for (int jj = 0; jj < 4; ++jj) {
        union { f16x8 v; uint2 u2[2]; } vF;
        const _Float16* vp = &Vsh[(16 * jj + c) * 132 + kb + g * 8];
        vF.u2[0] = *(const uint2*)vp;
        vF.u2[1] = *(const uint2*)(vp + 4);
        accO[hi][jj] = __builtin_amdgcn_mfma_f32_16x16x32_f16(pF.v, vF.v, accO[hi][jj], 0, 0, 0);
      }
    }
  }

  // ---- epilogue: normalize, store f16 for both h rows ----
#pragma unroll
  for (int hi = 0; hi < 2; ++hi) {
    _Float16* ob = outh + ((size_t)b * NN + (h0 + hi) * Ww + w0) * Cc + head * HD;
#pragma unroll
    for (int r = 0; r < 4; ++r) {
      const float inv = 1.f / s_run[hi][r];
      const int q = g * 4 + r;
#pragma unroll
      for (int jj = 0; jj < 4; ++jj)
        ob[(size_t)q * Cc + 16 * jj + c] = (_Float16)(accO[hi][jj][r] * inv);
    }
  }
}

// ---------------------------------------------------------------------------
extern "C" void kernel_launch(void* const* d_in, const int* in_sizes, int n_in,
                              void* d_out, int out_size, void* d_ws, size_t ws_size,
                              hipStream_t stream)
{
  const float* x      = (const float*)d_in[0];   // [32,1024,512]
  const float* w_qkv  = (const float*)d_in[1];   // [512,1536]
  const float* w_proj = (const float*)d_in[2];   // [512,512]
  const float* b_proj = (const float*)d_in[3];   // [512]
  float* out = (float*)d_out;

  const int M = Bsz * NN;                        // 32768
  char* ws = (char*)d_ws;
  _Float16* xh    = (_Float16*)ws;                              // 33.55 MB
  _Float16* qkvh  = (_Float16*)(ws + 33554432);                 // 100.66 MB
  _Float16* attnh = (_Float16*)(ws + 33554432 + 100663296);     // 33.55 MB
  _Float16* wqT   = (_Float16*)(ws + 167772160);                // 1.57 MB
  _Float16* wpT   = (_Float16*)(ws + 167772160 + 1572864);      // 0.52 MB

  // converts
  cvt_f32_f16<<<(M * Cc / 4 + 255) / 256, 256, 0, stream>>>(x, xh, M * Cc / 4);
  tcvt<<<(ROWS * Cc + 255) / 256, 256, 0, stream>>>(w_qkv, wqT, ROWS, Cc);
  tcvt<<<(Cc * Cc + 255) / 256, 256, 0, stream>>>(w_proj, wpT, Cc, Cc);

  // qkv = x @ w_qkv   (f16 out)
  gemm_mfma<true, false><<<dim3(ROWS / 128, M / 128), 256, 0, stream>>>(
      xh, wqT, nullptr, qkvh, ROWS, Cc);

  // local attention (MFMA, h-paired, K-dbuf, no-hoist) -> f16 [32768,512]
  local_attn_mfma<<<dim3(Hh / 2, NHEAD, Bsz), 512, 0, stream>>>(qkvh, attnh);

  // out = attn @ w_proj + bias  (f32 out)
  gemm_mfma<false, true><<<dim3(Cc / 128, M / 128), 256, 0, stream>>>(
      attnh, wpT, b_proj, out, Cc, Cc);
}